// Round 3
// baseline (87.548 us; speedup 1.0000x reference)
//
#include <hip/hip_runtime.h>
#include <hip/hip_bf16.h>

#define B_ 32
#define T_ 256
#define NIN_ 128
#define H_ 32
#define NOUT_ 128
#define R_ (B_ * T_)   // 8192 rows

#define C2L2E 2.88539008177792681472f   // 2*log2(e)

__device__ __forceinline__ float rfl(float x) {
    return __uint_as_float(__builtin_amdgcn_readfirstlane(__float_as_uint(x)));
}

// sigmoid-like core: rcp(exp2(o*2log2e + hpre) + 1), where hpre = hi*2log2e.
// tanh(hi+o) = 1 - 2*sig ; folded into the accumulation algebra.
__device__ __forceinline__ float sig_core(float o, float hpre) {
    float ex = __builtin_amdgcn_exp2f(fmaf(o, C2L2E, hpre));
    return __builtin_amdgcn_rcpf(ex + 1.0f);
}

// ---------------------------------------------------------------------------
// Fused kernel 1: per block = 8 rows x 32 h.
//   y = x @ W_in^T + b_in  (stage in LDS) ; h = y @ W_h^T ; o = y @ W_o^T
// ---------------------------------------------------------------------------
__global__ void __launch_bounds__(256) k_yho(
        const float* __restrict__ x,
        const float* __restrict__ W_in,
        const float* __restrict__ b_in,
        const float* __restrict__ W_h,
        const float* __restrict__ W_o,
        float* __restrict__ y,
        float* __restrict__ h,
        float* __restrict__ o) {
    __shared__ float ys[8][H_];
    const int t   = threadIdx.x;
    const int r   = t >> 5;              // local row 0..7
    const int hh  = t & 31;
    const int row = blockIdx.x * 8 + r;

    // y = x @ W_in^T + b_in  (x row broadcast across the 32-lane group)
    {
        const float4* x4 = reinterpret_cast<const float4*>(x + row * NIN_);
        const float4* w4 = reinterpret_cast<const float4*>(W_in + hh * NIN_);
        float a0 = b_in[hh], a1 = 0.f;
        #pragma unroll
        for (int k = 0; k < NIN_ / 8; ++k) {
            float4 xv0 = x4[2 * k],     wv0 = w4[2 * k];
            float4 xv1 = x4[2 * k + 1], wv1 = w4[2 * k + 1];
            a0 += xv0.x * wv0.x + xv0.y * wv0.y + xv0.z * wv0.z + xv0.w * wv0.w;
            a1 += xv1.x * wv1.x + xv1.y * wv1.y + xv1.z * wv1.z + xv1.w * wv1.w;
        }
        float acc = a0 + a1;
        ys[r][hh] = acc;
        y[row * H_ + hh] = acc;
    }
    __syncthreads();

    // h, o projections from the LDS-staged y row
    {
        const float4* y4  = reinterpret_cast<const float4*>(&ys[r][0]);
        const float4* wh4 = reinterpret_cast<const float4*>(W_h + hh * H_);
        const float4* wo4 = reinterpret_cast<const float4*>(W_o + hh * H_);
        float ah0 = 0.f, ah1 = 0.f, ao0 = 0.f, ao1 = 0.f;
        #pragma unroll
        for (int k = 0; k < H_ / 8; ++k) {
            float4 yv0 = y4[2 * k],     hv0 = wh4[2 * k],     ov0 = wo4[2 * k];
            float4 yv1 = y4[2 * k + 1], hv1 = wh4[2 * k + 1], ov1 = wo4[2 * k + 1];
            ah0 += yv0.x * hv0.x + yv0.y * hv0.y + yv0.z * hv0.z + yv0.w * hv0.w;
            ah1 += yv1.x * hv1.x + yv1.y * hv1.y + yv1.z * hv1.z + yv1.w * hv1.w;
            ao0 += yv0.x * ov0.x + yv0.y * ov0.y + yv0.z * ov0.z + yv0.w * ov0.w;
            ao1 += yv1.x * ov1.x + yv1.y * ov1.y + yv1.z * ov1.z + yv1.w * ov1.w;
        }
        h[row * H_ + hh] = ah0 + ah1;
        o[row * H_ + hh] = ao0 + ao1;
    }
}

// ---------------------------------------------------------------------------
// Kernel 2: per (b,i) block of 256 threads.
//   e_j = V.tanh(h_i + o_j)  with h_i,V in SGPRs (block-uniform):
//     e_j = sum_k V[k] + sum_k (-2 V[k]) * rcp(exp2((h_i[k]+o_j[k])*2log2e)+1)
// ---------------------------------------------------------------------------
__global__ void __launch_bounds__(256) k_att(
        const float* __restrict__ y,
        const float* __restrict__ h,
        const float* __restrict__ o,
        const float* __restrict__ V,
        const float* __restrict__ W_out,
        const float* __restrict__ b_out,
        float* __restrict__ out) {
    __shared__ float att[T_];
    __shared__ float red[8];
    __shared__ float cpart[8][H_];
    __shared__ float ctx[H_];

    const int bi = blockIdx.x;           // 0 .. B*T-1
    const int bb = bi >> 8;              // batch
    const int ii = bi & 255;             // query index i
    const int t  = threadIdx.x;          // 0..255 ; doubles as key index j

    // ---- block-uniform scalars: hi[k]*2log2e, -2V[k], sum(V) ----
    const float* hrow = h + (bb * T_ + ii) * H_;
    float hs[H_];   // SGPR after readfirstlane
    float w2[H_];
    float vsum = 0.f;
    #pragma unroll
    for (int k = 0; k < H_; ++k) {
        hs[k] = rfl(hrow[k] * C2L2E);
        float vk = V[k];
        w2[k] = rfl(vk * -2.0f);
        vsum += vk;
    }
    vsum = rfl(vsum);

    // ---- prefetch o_j row (8 x float4 = 32 regs) ----
    const float4* o4 = reinterpret_cast<const float4*>(o + (bb * T_ + t) * H_);
    float4 ov[8];
    #pragma unroll
    for (int q = 0; q < 8; ++q) ov[q] = o4[q];

    // ---- e_j with 4 independent accumulators ----
    float e0 = 0.f, e1 = 0.f, e2 = 0.f, e3 = 0.f;
    #pragma unroll
    for (int q = 0; q < 8; ++q) {
        e0 = fmaf(w2[4 * q + 0], sig_core(ov[q].x, hs[4 * q + 0]), e0);
        e1 = fmaf(w2[4 * q + 1], sig_core(ov[q].y, hs[4 * q + 1]), e1);
        e2 = fmaf(w2[4 * q + 2], sig_core(ov[q].z, hs[4 * q + 2]), e2);
        e3 = fmaf(w2[4 * q + 3], sig_core(ov[q].w, hs[4 * q + 3]), e3);
    }
    float e = ((e0 + e1) + (e2 + e3)) + vsum;

    // ---- block max ----
    float m = e;
    #pragma unroll
    for (int off = 1; off < 64; off <<= 1)
        m = fmaxf(m, __shfl_xor(m, off));
    if ((t & 63) == 0) red[t >> 6] = m;
    __syncthreads();
    m = fmaxf(fmaxf(red[0], red[1]), fmaxf(red[2], red[3]));

    // ---- block sum of exp(e-m) ----
    float s = __builtin_amdgcn_exp2f((e - m) * 1.44269504088896341f);
    float ssum = s;
    #pragma unroll
    for (int off = 1; off < 64; off <<= 1)
        ssum += __shfl_xor(ssum, off);
    if ((t & 63) == 0) red[4 + (t >> 6)] = ssum;
    __syncthreads();
    float S = (red[4] + red[5]) + (red[6] + red[7]);
    float lse = m + __builtin_amdgcn_logf(S) * 0.69314718055994531f;

    att[t] = e - lse;   // log-probabilities (faithful to reference)
    __syncthreads();

    // ---- context: ctx[h] = sum_j att[j] * y[b,j,h] ----
    {
        int hh    = t & 31;
        int chunk = t >> 5;      // 8 chunks of 32 j's
        float acc = 0.f;
        #pragma unroll
        for (int jj = 0; jj < 32; ++jj) {
            int j = (chunk << 5) + jj;
            acc += att[j] * y[(bb * T_ + j) * H_ + hh];
        }
        cpart[chunk][hh] = acc;
    }
    __syncthreads();
    if (t < H_) {
        float acc = 0.f;
        #pragma unroll
        for (int c = 0; c < 8; ++c) acc += cpart[c][t];
        ctx[t] = acc;
    }
    __syncthreads();

    // ---- output projection: 128 outputs ----
    if (t < NOUT_) {
        const float4* w4 = reinterpret_cast<const float4*>(W_out + t * H_);
        float acc = b_out[t];
        #pragma unroll
        for (int k = 0; k < H_ / 4; ++k) {
            float4 wv = w4[k];
            float4 cv = *reinterpret_cast<const float4*>(&ctx[k * 4]);
            acc += wv.x * cv.x + wv.y * cv.y + wv.z * cv.z + wv.w * cv.w;
        }
        out[(bb * T_ + ii) * NOUT_ + t] = acc;
    }
}

// ---------------------------------------------------------------------------
extern "C" void kernel_launch(void* const* d_in, const int* in_sizes, int n_in,
                              void* d_out, int out_size, void* d_ws, size_t ws_size,
                              hipStream_t stream) {
    const float* x     = (const float*)d_in[0];
    const float* W_in  = (const float*)d_in[1];
    const float* b_in  = (const float*)d_in[2];
    const float* W_h   = (const float*)d_in[3];
    const float* W_o   = (const float*)d_in[4];
    const float* V     = (const float*)d_in[5];
    const float* W_out = (const float*)d_in[6];
    const float* b_out = (const float*)d_in[7];
    float* out = (float*)d_out;

    // workspace layout: y | h | o  (each R_*H_ floats = 1 MB)
    float* y = (float*)d_ws;
    float* h = y + R_ * H_;
    float* o = h + R_ * H_;

    k_yho<<<R_ / 8, 256, 0, stream>>>(x, W_in, b_in, W_h, W_o, y, h, o);
    k_att<<<R_, 256, 0, stream>>>(y, h, o, V, W_out, b_out, out);
}